// Round 16
// baseline (192.814 us; speedup 1.0000x reference)
//
#include <hip/hip_runtime.h>
#include <hip/hip_bf16.h>
#include <math.h>

// Problem constants
#define NB    16
#define NSEQ  2048
#define MROWS (NB*NSEQ)        // 32768

typedef __attribute__((ext_vector_type(8))) short bf16x8;
typedef __attribute__((ext_vector_type(4))) float f32x4;

__device__ __forceinline__ void g2l16(const void* g, void* l) {
    __builtin_amdgcn_global_load_lds(
        (const __attribute__((address_space(1))) void*)g,
        (__attribute__((address_space(3))) void*)l, 16, 0, 0);
}

__device__ __forceinline__ ushort f2bfu(float x) {
    __hip_bfloat16 t = __float2bfloat16(x);
    return *reinterpret_cast<ushort*>(&t);
}

// ---------------------------------------------------------------------------
// Fused preps: [0,4096) x->Xb; [4096,4224) Wv cast; [4224,4352) Wqk cast;
// [4352,4872) Gcat; [4872,4888) Fcs; [4888,4898) Bas DFT basis table.
// ---------------------------------------------------------------------------
__global__ __launch_bounds__(256) void k_misc(const float* __restrict__ x,
                                              const float* __restrict__ wqkv,
                                              const float* __restrict__ wout,
                                              __hip_bfloat16* __restrict__ Xb,
                                              ushort* __restrict__ Wvb,
                                              ushort* __restrict__ Wqkb,
                                              ushort* __restrict__ Gcat,
                                              ushort* __restrict__ Fcs,
                                              ushort* __restrict__ Bas) {
    __shared__ float tc[128], ts[128];
    int tid = threadIdx.x;
    int bid = blockIdx.x;
    if (bid < 4096) {
        int i = bid * 256 + tid;
        float4 v = ((const float4*)x)[i];
        __hip_bfloat16 o[4] = {__float2bfloat16(v.x), __float2bfloat16(v.y),
                               __float2bfloat16(v.z), __float2bfloat16(v.w)};
        *(ushort4*)((ushort*)Xb + (size_t)i * 4) = *(const ushort4*)o;
    } else if (bid < 4224) {
        int u = bid - 4096;                // 0..127
        float4 v = *(const float4*)(wqkv + (size_t)u * 3072 + 2048 + tid * 4);
        ushort o[4] = {f2bfu(v.x), f2bfu(v.y), f2bfu(v.z), f2bfu(v.w)};
        *(ushort4*)(Wvb + (size_t)u * 1024 + tid * 4) = *(const ushort4*)o;
    } else if (bid < 4352) {
        int u = bid - 4224;                // 0..127: q/k cols 0..2047 of row u
        #pragma unroll
        for (int it = 0; it < 2; ++it) {
            int i = it * 256 + tid;        // float4 idx 0..511
            float4 v = ((const float4*)(wqkv + (size_t)u * 3072))[i];
            ushort o[4] = {f2bfu(v.x), f2bfu(v.y), f2bfu(v.z), f2bfu(v.w)};
            *(ushort4*)(Wqkb + (size_t)u * 2048 + i * 4) = *(const ushort4*)o;
        }
    } else if (bid < 4872) {
        int hx = bid - 4352;               // 0..519
        if (tid < 128) {
            float a = (float)tid / 64.0f;
            tc[tid] = cospif(a);
            ts[tid] = sinpif(a);
        }
        __syncthreads();
        if (tid < 128) {
            int h = hx / 65, xx = hx - h * 65;
            float w = (xx == 0 || xx == 64) ? (1.0f / 128.0f) : (2.0f / 128.0f);
            float ar = 0.f, ai = 0.f;
            #pragma unroll 8
            for (int d = 0; d < 128; ++d) {
                float wv = wout[(size_t)(h * 128 + d) * 128 + tid];
                int m = (xx * d) & 127;
                ar = fmaf(wv, tc[m], ar);
                ai = fmaf(wv, ts[m], ai);
            }
            ushort* gp = Gcat + ((size_t)(h * 128 + tid)) * 160;
            gp[xx] = f2bfu(ar * w);
            gp[80 + xx] = f2bfu(-ai * w);
            if (xx == 0) {
                for (int k = 65; k < 80; ++k) gp[k] = 0;
                for (int k = 145; k < 160; ++k) gp[k] = 0;
            }
        }
    } else if (bid < 4888) {
        // Fcs[r][y]: r<128 cos(2pi r y/128); r>=128 -sin(...); y>=65 -> 0
        int r = (bid - 4872) * 16 + (tid >> 4);
        int d = r & 127;
        int y0 = (tid & 15) * 6;
        #pragma unroll
        for (int k = 0; k < 6; ++k) {
            int y = y0 + k;
            float v = 0.f;
            if (y < 65) {
                float a = (float)((d * y) & 127) / 64.0f;
                v = (r < 128) ? cospif(a) : -sinpif(a);
            }
            Fcs[r * 96 + y] = f2bfu(v);
        }
    } else {
        // Bas[rj][d]: rj<80 -> cos(2pi f d/128)/65, rj>=80 -> -sin(...)/65, f=rj%80
        int idx = bid - 4888;              // 0..9
        int rj = idx * 16 + (tid >> 4);
        int ri = (rj >= 80) ? 1 : 0;
        int f = rj - ri * 80;
        int d0 = (tid & 15) * 8;
        #pragma unroll
        for (int k = 0; k < 8; ++k) {
            int d = d0 + k;
            float a = (float)((f * d) & 127) / 64.0f;
            float v = (ri ? -sinpif(a) : cospif(a)) * (1.0f / 65.0f);
            Bas[rj * 128 + d] = f2bfu(v);
        }
    }
}

// ---------------------------------------------------------------------------
// Weight DFT fold via MFMA. Grid 32: one block per (reg,h,uh): 64 u-rows.
// C[u][rj] = sum_d Wqkb[u][reg*1024+h*128+d] * Bas[rj][d]. M=64, N=160, K=128.
// Per-head layout Wt2[h][n = reg*160 + rj][u], rj = f + 80*ri.
// ---------------------------------------------------------------------------
__global__ __launch_bounds__(256) void k_wfold(const ushort* __restrict__ Wqkb,
                                               const ushort* __restrict__ Bas,
                                               ushort* __restrict__ Wt2) {
    __shared__ ushort As[64 * 128];
    __shared__ ushort Bs[160 * 128];
    int tid = threadIdx.x;
    int wave = tid >> 6, lane = tid & 63;
    int reg = blockIdx.x >> 4;
    int h = (blockIdx.x >> 1) & 7;
    int uh = blockIdx.x & 1;
    const ushort* ga = Wqkb + (size_t)(uh * 64) * 2048 + reg * 1024 + h * 128;
    #pragma unroll
    for (int it = 0; it < 4; ++it) {
        int q0 = wave * 256 + it * 64;
        int q = q0 + lane;
        int row = q >> 4, cp = q & 15;
        int gc = cp ^ (row & 15);
        g2l16(ga + (size_t)row * 2048 + gc * 8, As + q0 * 8);
    }
    #pragma unroll
    for (int it = 0; it < 10; ++it) {
        int q0 = it * 256 + wave * 64;
        int q = q0 + lane;
        int row = q >> 4, cp = q & 15;
        int gc = cp ^ (row & 15);
        g2l16(Bas + (size_t)row * 128 + gc * 8, Bs + q0 * 8);
    }
    __syncthreads();

    f32x4 acc[2][5];
    #pragma unroll
    for (int i = 0; i < 2; ++i)
        #pragma unroll
        for (int j = 0; j < 5; ++j) acc[i][j] = (f32x4){0.f, 0.f, 0.f, 0.f};

    int lr = lane & 15, lk = lane >> 4;
    int wr = (wave >> 1) * 32;             // m (u) offset within 64
    int wn = (wave & 1) * 80;              // n (rj) offset
    #pragma unroll
    for (int kk = 0; kk < 4; ++kk) {
        bf16x8 af[2], bfr[5];
        int c = kk * 4 + lk;
        #pragma unroll
        for (int i = 0; i < 2; ++i) {
            int m = wr + i * 16 + lr;
            af[i] = *(const bf16x8*)(As + m * 128 + (c ^ (m & 15)) * 8);
        }
        #pragma unroll
        for (int j = 0; j < 5; ++j) {
            int n = wn + j * 16 + lr;
            bfr[j] = *(const bf16x8*)(Bs + n * 128 + (c ^ (n & 15)) * 8);
        }
        #pragma unroll
        for (int i = 0; i < 2; ++i)
            #pragma unroll
            for (int j = 0; j < 5; ++j)
                acc[i][j] = __builtin_amdgcn_mfma_f32_16x16x32_bf16(af[i], bfr[j], acc[i][j], 0, 0, 0);
    }

    #pragma unroll
    for (int j = 0; j < 5; ++j) {
        int rj = wn + j * 16 + lr;
        int n = (h * 2 + reg) * 160 + rj;
        #pragma unroll
        for (int i = 0; i < 2; ++i) {
            int c0 = uh * 64 + wr + i * 16 + lk * 4;
            union { ushort4 u4; ushort u[4]; } pk;
            #pragma unroll
            for (int r = 0; r < 4; ++r) pk.u[r] = f2bfu(acc[i][j][r]);
            *(ushort4*)(Wt2 + (size_t)n * 128 + c0) = pk.u4;
        }
    }
}

// ---------------------------------------------------------------------------
// FUSED gemm1 + magnitude + QK^T, v9: v7's wave-split registers (the only
// proven lever: more waves, same per-wave efficiency) on v4's 64-e geometry.
// As[64x128] 16 KB + S[160][64] 20 KB = 36 KB -> 3 blocks/CU = 30 waves/CU
// (was 2 blocks / 20 nominal, ~7.5 effective). bw[4][2] loaded ONCE (v4's
// failure was per-pass reloads — absent here). Grid (128,8): (b,h,epart),
// 256 e/block = 4 iters of 64 e; 8 attp partials (round-12 softmax, proven).
// setprio removed (round-15 A/B: null).
// ---------------------------------------------------------------------------
__global__ __launch_bounds__(640, 8) void k_fuse(const __hip_bfloat16* __restrict__ Xb,
                                                 const ushort* __restrict__ Wt2,
                                                 float* __restrict__ attp) {
    __shared__ ushort As[64 * 128];     // 16 KB
    __shared__ ushort S[160 * 64];      // 20 KB
    int tid = threadIdx.x;
    int wave = tid >> 6, lane = tid & 63;   // 10 waves
    int lr = lane & 15, lk = lane >> 4;
    int g = wave >> 1;                      // freq-tile 0..4
    int half = wave & 1;                    // stage1 rb-half / QK^T kt-half
    int lin = blockIdx.y * 128 + blockIdx.x;
    int nl = (lin & 7) * 128 + (lin >> 3);  // bijective: 1024 = 8*128
    int b = nl >> 6;                        // XCD gets 2 b's: X slices L2-local
    int rem = nl & 63;
    int h = rem >> 3, epart = rem & 7;
    size_t erow0 = (size_t)b * NSEQ + (size_t)epart * 256;
    const ushort* wh = Wt2 + (size_t)h * 320 * 128;

    // B-fragments: wave (g,half) holds rb = half*2 + j (j=0 re, j=1 im)
    bf16x8 bw[4][2];
    #pragma unroll
    for (int ks = 0; ks < 4; ++ks)
        #pragma unroll
        for (int j = 0; j < 2; ++j) {
            int n = (half * 2 + j) * 80 + g * 16 + lr;
            bw[ks][j] = *(const bf16x8*)(wh + (size_t)n * 128 + (ks * 4 + lk) * 8);
        }

    // stage As(0): 64 e-rows, 1024 16B-chunks over 10 waves
    {
        const ushort* gx = (const ushort*)Xb + erow0 * 128;
        for (int r = wave; r < 16; r += 10) {
            int q0 = r * 64, q = q0 + lane;
            int row = q >> 4, cp = q & 15;
            int gc = cp ^ (row & 15);
            g2l16(gx + (size_t)row * 128 + gc * 8, As + q0 * 8);
        }
    }
    __syncthreads();

    f32x4 acc2[3];
    #pragma unroll
    for (int j = 0; j < 3; ++j) acc2[j] = (f32x4){0.f, 0.f, 0.f, 0.f};

    int srow = half * 80 + g * 16 + lr;    // stage-1 mag destination row
    int sw = srow & 7;                     // 8-deep XOR swizzle (64-wide S)
    int ktb = half * 3;                    // QK^T kt base (0 or 3)
    int nkt = half ? 2 : 3;

    for (int it = 0; it < 4; ++it) {
        // ---- stage1 + mags: wave's (g, q/k) pair for this 64-e chunk
        #pragma unroll
        for (int et = 0; et < 4; ++et) {
            f32x4 a2[2];
            a2[0] = (f32x4){0.f, 0.f, 0.f, 0.f};
            a2[1] = (f32x4){0.f, 0.f, 0.f, 0.f};
            #pragma unroll
            for (int ks = 0; ks < 4; ++ks) {
                int m = et * 16 + lr;
                bf16x8 xa = *(const bf16x8*)(As + m * 128 + (((ks * 4 + lk) ^ (m & 15))) * 8);
                a2[0] = __builtin_amdgcn_mfma_f32_16x16x32_bf16(xa, bw[ks][0], a2[0], 0, 0, 0);
                a2[1] = __builtin_amdgcn_mfma_f32_16x16x32_bf16(xa, bw[ks][1], a2[1], 0, 0, 0);
            }
            int e4 = et * 16 + lk * 4;
            int cq = e4 >> 3, sub = e4 & 7;
            union { ushort4 u4; ushort u[4]; } pm;
            #pragma unroll
            for (int r = 0; r < 4; ++r)
                pm.u[r] = f2bfu(__builtin_amdgcn_sqrtf(a2[0][r] * a2[0][r] + a2[1][r] * a2[1][r]));
            *(ushort4*)(S + srow * 64 + ((cq ^ sw) << 3) + sub) = pm.u4;
        }
        __syncthreads();                 // S complete; As reads done
        if (it < 3) {
            // prefetch As(it+1); latency hides under QK^T, drained at barrier
            const ushort* gx = (const ushort*)Xb + (erow0 + (size_t)(it + 1) * 64) * 128;
            for (int r = wave; r < 16; r += 10) {
                int q0 = r * 64, q = q0 + lane;
                int row = q >> 4, cp = q & 15;
                int gc = cp ^ (row & 15);
                g2l16(gx + (size_t)row * 128 + gc * 8, As + q0 * 8);
            }
        }
        // ---- QK^T: wave (g,half) -> q-tile g, kt subset, K=64 (this iter)
        #pragma unroll
        for (int ks = 0; ks < 2; ++ks) {
            int cg = ks * 4 + lk;
            int xr = g * 16 + lr;
            bf16x8 qa = *(const bf16x8*)(S + xr * 64 + ((cg ^ (xr & 7)) << 3));
            #pragma unroll
            for (int j = 0; j < 3; ++j) {
                if (j < nkt) {
                    int kt = ktb + j;
                    int yr = 80 + kt * 16 + lr;
                    bf16x8 kb = *(const bf16x8*)(S + yr * 64 + ((cg ^ (yr & 7)) << 3));
                    acc2[j] = __builtin_amdgcn_mfma_f32_16x16x32_bf16(qa, kb, acc2[j], 0, 0, 0);
                }
            }
        }
        __syncthreads();                 // S reads done; As(it+1) drained
    }

    float* outp = attp + ((size_t)(b * 8 + h) * 8 + epart) * 6400;
    #pragma unroll
    for (int j = 0; j < 3; ++j) {
        if (j < nkt) {
            int kt = ktb + j;
            #pragma unroll
            for (int r = 0; r < 4; ++r)
                outp[(g * 16 + lk * 4 + r) * 80 + kt * 16 + lr] = acc2[j][r];
        }
    }
}

// ---------------------------------------------------------------------------
// Sum 8 partials + softmax over y -> AttB bf16 [80x104] zero-padded.
// ---------------------------------------------------------------------------
__global__ void k_softmax(const float* __restrict__ attp, ushort* __restrict__ AttB) {
    int xx = blockIdx.x;                   // 0..79
    int bh = blockIdx.y;                   // 0..127
    int lane = threadIdx.x;                // 64
    ushort* Ab = AttB + (size_t)bh * 8320;
    if (xx >= 65) {
        Ab[xx * 104 + lane] = 0;
        if (lane < 40) Ab[xx * 104 + 64 + lane] = 0;
        return;
    }
    const float* base = attp + (size_t)bh * 8 * 6400 + xx * 80;
    float v0 = 0.f, v1 = 0.f;
    #pragma unroll
    for (int c = 0; c < 8; ++c) {
        v0 += base[(size_t)c * 6400 + lane];
        if (lane == 0) v1 += base[(size_t)c * 6400 + 64];
    }
    float v1b = __shfl(v1, 0);
    float m = fmaxf(v0, v1b);
    #pragma unroll
    for (int off = 32; off >= 1; off >>= 1) m = fmaxf(m, __shfl_xor(m, off));
    float e0 = expf(v0 - m);
    float e1 = expf(v1b - m);
    float s = e0;
    #pragma unroll
    for (int off = 32; off >= 1; off >>= 1) s += __shfl_xor(s, off);
    s += e1;
    float inv = 1.0f / s;
    Ab[xx * 104 + lane] = f2bfu(e0 * inv);
    if (lane == 0) Ab[xx * 104 + 64] = f2bfu(e1 * inv);
    if (lane < 39) Ab[xx * 104 + 65 + lane] = 0;
}

// ---------------------------------------------------------------------------
// Fused T+P per (chalf, bh) block (reads bf16 AttB straight from global):
// Stage 1: [Fc;Fs][256,96] @ AttB^T -> A3 via LDS (C->A layout, pads zeroed)
// Stage 2: A3[128,160] @ Gcat^T -> Pt[b][c][h*128+d]
// ---------------------------------------------------------------------------
__global__ __launch_bounds__(256) void k_TP(const ushort* __restrict__ AttB,
                                            const ushort* __restrict__ Fcs,
                                            const ushort* __restrict__ Gcat,
                                            ushort* __restrict__ Pt) {
    __shared__ ushort A3[128 * 168];
    int tid = threadIdx.x;
    int wave = tid >> 6, lane = tid & 63;
    int lr = lane & 15, quad = lane >> 4;
    int chalf = blockIdx.x, bh = blockIdx.y;
    int b = bh >> 3, h = bh & 7;

    uint2 z2; z2.x = 0; z2.y = 0;
    uint2* A3v = (uint2*)A3;
    #pragma unroll 4
    for (int i = tid; i < 128 * 168 / 4; i += 256) A3v[i] = z2;
    __syncthreads();
    const ushort* Ab = AttB + (size_t)bh * 8320;

    // stage 1
    f32x4 acc1[4][5];
    #pragma unroll
    for (int i = 0; i < 4; ++i)
        #pragma unroll
        for (int j = 0; j < 5; ++j) acc1[i][j] = (f32x4){0.f, 0.f, 0.f, 0.f};
    #pragma unroll
    for (int ks = 0; ks < 3; ++ks) {
        bf16x8 af[4], bfr[5];
        #pragma unroll
        for (int mi = 0; mi < 4; ++mi)
            af[mi] = *(const bf16x8*)(Fcs + (size_t)((wave * 4 + mi) * 16 + lr) * 96 + ks * 32 + quad * 8);
        #pragma unroll
        for (int nt = 0; nt < 5; ++nt)
            bfr[nt] = *(const bf16x8*)(Ab + (nt * 16 + lr) * 104 + ks * 32 + quad * 8);
        #pragma unroll
        for (int mi = 0; mi < 4; ++mi)
            #pragma unroll
            for (int nt = 0; nt < 5; ++nt)
                acc1[mi][nt] = __builtin_amdgcn_mfma_f32_16x16x32_bf16(af[mi], bfr[nt], acc1[mi][nt], 0, 0, 0);
    }
    #pragma unroll
    for (int nt = 0; nt < 5; ++nt) {
        int x = nt * 16 + lr;
        if (x < 65) {
            #pragma unroll
            for (int mi = 0; mi < 4; ++mi) {
                int wbase = (wave * 4 + mi) * 16 + quad * 4;
                #pragma unroll
                for (int r = 0; r < 4; ++r) {
                    int which = wbase + r;
                    int d = which & 127;
                    int kc = (which >> 7) * 80 + x;
                    A3[d * 168 + kc] = f2bfu(acc1[mi][nt][r]);
                }
            }
        }
    }
    __syncthreads();

    // stage 2
    f32x4 acc2[2][4];
    #pragma unroll
    for (int i = 0; i < 2; ++i)
        #pragma unroll
        for (int j = 0; j < 4; ++j) acc2[i][j] = (f32x4){0.f, 0.f, 0.f, 0.f};
    const ushort* Gh = Gcat + (size_t)h * 128 * 160;
    #pragma unroll
    for (int ks = 0; ks < 5; ++ks) {
        bf16x8 a2[2], b2[4];
        #pragma unroll
        for (int mi = 0; mi < 2; ++mi)
            a2[mi] = *(const bf16x8*)(A3 + ((wave * 2 + mi) * 16 + lr) * 168 + ks * 32 + quad * 8);
        #pragma unroll
        for (int nt = 0; nt < 4; ++nt)
            b2[nt] = *(const bf16x8*)(Gh + (size_t)(chalf * 64 + nt * 16 + lr) * 160 + ks * 32 + quad * 8);
        #pragma unroll
        for (int mi = 0; mi < 2; ++mi)
            #pragma unroll
            for (int nt = 0; nt < 4; ++nt)
                acc2[mi][nt] = __builtin_amdgcn_mfma_f32_16x16x32_bf16(a2[mi], b2[nt], acc2[mi][nt], 0, 0, 0);
    }
    #pragma unroll
    for (int mi = 0; mi < 2; ++mi) {
        int dbase = (wave * 2 + mi) * 16 + quad * 4;
        #pragma unroll
        for (int nt = 0; nt < 4; ++nt) {
            int c = chalf * 64 + nt * 16 + lr;
            union { ushort4 u4; ushort u[4]; } pk;
            #pragma unroll
            for (int r = 0; r < 4; ++r) pk.u[r] = f2bfu(acc2[mi][nt][r]);
            *(ushort4*)(Pt + ((size_t)(b * 128 + c)) * 1024 + h * 128 + dbase) = pk.u4;
        }
    }
}

// ---------------------------------------------------------------------------
// R_b = Wv @ P_b folded: Rt_b[n][u] = sum_vc Wvb[u][vc] * Pt_b[n][vc].
// Grid 64: (b, nq, uq) -> 64x64 output quadrant.
// ---------------------------------------------------------------------------
__global__ __launch_bounds__(256) void k_R(const ushort* __restrict__ Wvb,
                                           const ushort* __restrict__ Pt,
                                           ushort* __restrict__ Rt) {
    __shared__ ushort As[64 * 128];
    __shared__ ushort Bs[64 * 128];
    int tid = threadIdx.x;
    int wave = tid >> 6, lane = tid & 63;
    int b = blockIdx.x >> 2;
    int nq = (blockIdx.x >> 1) & 1;
    int uq = blockIdx.x & 1;
    const ushort* pb = Pt + (size_t)b * 128 * 1024;

    f32x4 acc[2][2];
    #pragma unroll
    for (int i = 0; i < 2; ++i)
        #pragma unroll
        for (int j = 0; j < 2; ++j) acc[i][j] = (f32x4){0.f, 0.f, 0.f, 0.f};

    int lr = lane & 15, lk = lane >> 4;
    int wr = (wave >> 1) * 32, wc = (wave & 1) * 32;

    for (int k0 = 0; k0 < 1024; k0 += 128) {
        __syncthreads();
        #pragma unroll
        for (int it = 0; it < 4; ++it) {
            int q = wave * 256 + it * 64 + lane;
            int row = q >> 4, cp = q & 15;
            int gc = cp ^ (row & 15);
            int lbase = (wave * 256 + it * 64) * 8;
            g2l16(Wvb + (size_t)(uq * 64 + row) * 1024 + k0 + gc * 8, As + lbase);
            g2l16(pb + (size_t)(nq * 64 + row) * 1024 + k0 + gc * 8, Bs + lbase);
        }
        __syncthreads();
        #pragma unroll
        for (int kk = 0; kk < 4; ++kk) {
            bf16x8 af[2], bfr[2];
            int c = kk * 4 + lk;
            #pragma unroll
            for (int i = 0; i < 2; ++i) {
                int m = wr + i * 16 + lr;
                af[i] = *(const bf16x8*)(As + m * 128 + (c ^ (m & 15)) * 8);
                int n = wc + i * 16 + lr;
                bfr[i] = *(const bf16x8*)(Bs + n * 128 + (c ^ (n & 15)) * 8);
            }
            #pragma unroll
            for (int i = 0; i < 2; ++i)
                #pragma unroll
                for (int j = 0; j < 2; ++j)
                    acc[i][j] = __builtin_amdgcn_mfma_f32_16x16x32_bf16(af[i], bfr[j], acc[i][j], 0, 0, 0);
        }
    }
    #pragma unroll
    for (int i = 0; i < 2; ++i) {
        int ubase = uq * 64 + wr + i * 16 + lk * 4;
        #pragma unroll
        for (int j = 0; j < 2; ++j) {
            int n = nq * 64 + wc + j * 16 + lr;
            union { ushort4 u4; ushort u[4]; } pk;
            #pragma unroll
            for (int r = 0; r < 4; ++r) pk.u[r] = f2bfu(acc[i][j][r]);
            *(ushort4*)(Rt + (size_t)b * 16384 + n * 128 + ubase) = pk.u4;
        }
    }
}

// ---------------------------------------------------------------------------
// out = Xb @ Rt_b^T + bias. M=32768 (128/block), N=128, K=128 one shot.
// ---------------------------------------------------------------------------
__global__ __launch_bounds__(256) void k_out(const __hip_bfloat16* __restrict__ Xb,
                                             const ushort* __restrict__ Rt,
                                             const float* __restrict__ bout,
                                             float* __restrict__ out) {
    __shared__ ushort As[128 * 128];
    __shared__ ushort Bs[128 * 128];
    int tid = threadIdx.x;
    int wave = tid >> 6, lane = tid & 63;
    int m0 = blockIdx.x * 128;
    int b = blockIdx.x >> 4;
    const ushort* ga = (const ushort*)Xb + (size_t)m0 * 128;
    const ushort* gb = Rt + (size_t)b * 16384;
    #pragma unroll
    for (int it = 0; it < 8; ++it) {
        int q = wave * 512 + it * 64 + lane;
        int row = q >> 4, cp = q & 15;
        int gc = cp ^ (row & 15);
        int lbase = (wave * 512 + it * 64) * 8;
        g2l16(ga + (size_t)row * 128 + gc * 8, As + lbase);
        g2l16(gb + (size_t)row * 128 + gc * 8, Bs + lbase);
    }
    __syncthreads();

    f32x4 acc[4][4];
    #pragma unroll
    for (int i = 0; i < 4; ++i)
        #pragma unroll
        for (int j = 0; j < 4; ++j) acc[i][j] = (f32x4){0.f, 0.f, 0.f, 0.f};

    int lr = lane & 15, lk = lane >> 4;
    int wr = (wave >> 1) * 64, wc = (wave & 1) * 64;
    #pragma unroll
    for (int kk = 0; kk < 4; ++kk) {
        bf16x8 af[4], bfr[4];
        int c = kk * 4 + lk;
        #pragma unroll
        for (int i = 0; i < 4; ++i) {
            int m = wr + i * 16 + lr;
            af[i] = *(const bf16x8*)(As + m * 128 + (c ^ (m & 15)) * 8);
            int n = wc + i * 16 + lr;
            bfr[i] = *(const bf16x8*)(Bs + n * 128 + (c ^ (n & 15)) * 8);
        }
        #pragma unroll
        for (int i = 0; i < 4; ++i)
            #pragma unroll
            for (int j = 0; j < 4; ++j)
                acc[i][j] = __builtin_amdgcn_mfma_f32_16x16x32_bf16(af[i], bfr[j], acc[i][j], 0, 0, 0);
    }

    #pragma unroll
    for (int i = 0; i < 4; ++i) {
        int gr = m0 + wr + i * 16 + lk * 4;
        #pragma unroll
        for (int j = 0; j < 4; ++j) {
            int gcol = wc + j * 16 + lr;
            float bias = bout[gcol];
            #pragma unroll
            for (int r = 0; r < 4; ++r)
                out[(size_t)(gr + r) * 128 + gcol] = acc[i][j][r] + bias;
        }
    }
}

extern "C" void kernel_launch(void* const* d_in, const int* in_sizes, int n_in,
                              void* d_out, int out_size, void* d_ws, size_t ws_size,
                              hipStream_t stream) {
    const float* x    = (const float*)d_in[0];
    const float* wqkv = (const float*)d_in[1];
    const float* wout = (const float*)d_in[2];
    const float* bout = (const float*)d_in[3];
    float* out = (float*)d_out;

    char* ws = (char*)d_ws;
    size_t off = 0;
    auto alloc = [&](size_t bytes) -> void* {
        void* p = (void*)(ws + off);
        off += (bytes + 255) & ~(size_t)255;
        return p;
    };
    ushort* Wt2  = (ushort*)alloc((size_t)8 * 320 * 128 * 2);                  // 640 KB
    ushort* Gcat = (ushort*)alloc((size_t)8 * 128 * 160 * 2);                  // 320 KB
    ushort* Fcs  = (ushort*)alloc((size_t)256 * 96 * 2);                       // 48 KB
    ushort* Wvb  = (ushort*)alloc((size_t)128 * 1024 * 2);                     // 256 KB
    ushort* Wqkb = (ushort*)alloc((size_t)128 * 2048 * 2);                     // 512 KB
    ushort* Bas  = (ushort*)alloc((size_t)160 * 128 * 2);                      // 40 KB
    __hip_bfloat16* Xb = (__hip_bfloat16*)alloc((size_t)MROWS * 128 * 2);      // 8.4 MB
    float* attp = (float*)alloc((size_t)128 * 8 * 6400 * 4);                   // 26.2 MB
    ushort* AttB = (ushort*)alloc((size_t)128 * 8320 * 2);                     // 2.13 MB
    ushort* Pt  = (ushort*)alloc((size_t)16 * 128 * 1024 * 2);                 // 4.2 MB
    ushort* Rt  = (ushort*)alloc((size_t)16 * 128 * 128 * 2);                  // 512 KB

    k_misc<<<dim3(4898), 256, 0, stream>>>(x, wqkv, wout, Xb, Wvb, Wqkb, Gcat, Fcs, Bas);
    k_wfold<<<dim3(32), 256, 0, stream>>>(Wqkb, Bas, Wt2);
    k_fuse<<<dim3(128, 8), 640, 0, stream>>>(Xb, Wt2, attp);
    k_softmax<<<dim3(80, 128), 64, 0, stream>>>(attp, AttB);
    k_TP<<<dim3(2, 128), 256, 0, stream>>>(AttB, Fcs, Gcat, Pt);
    k_R<<<dim3(64), 256, 0, stream>>>(Wvb, Pt, Rt);
    k_out<<<dim3(256), 256, 0, stream>>>(Xb, Rt, bout, out);
}

// Round 17
// 139.715 us; speedup vs baseline: 1.3801x; 1.3801x over previous
//
#include <hip/hip_runtime.h>
#include <hip/hip_bf16.h>
#include <math.h>

// Problem constants
#define NB    16
#define NSEQ  2048
#define MROWS (NB*NSEQ)        // 32768

typedef __attribute__((ext_vector_type(8))) short bf16x8;
typedef __attribute__((ext_vector_type(4))) float f32x4;

__device__ __forceinline__ void g2l16(const void* g, void* l) {
    __builtin_amdgcn_global_load_lds(
        (const __attribute__((address_space(1))) void*)g,
        (__attribute__((address_space(3))) void*)l, 16, 0, 0);
}

__device__ __forceinline__ ushort f2bfu(float x) {
    __hip_bfloat16 t = __float2bfloat16(x);
    return *reinterpret_cast<ushort*>(&t);
}

// ---------------------------------------------------------------------------
// Fused preps: [0,4096) x->Xb; [4096,4224) Wv cast; [4224,4352) Wqk cast;
// [4352,4872) Gcat; [4872,4888) Fcs; [4888,4898) Bas DFT basis table.
// ---------------------------------------------------------------------------
__global__ __launch_bounds__(256) void k_misc(const float* __restrict__ x,
                                              const float* __restrict__ wqkv,
                                              const float* __restrict__ wout,
                                              __hip_bfloat16* __restrict__ Xb,
                                              ushort* __restrict__ Wvb,
                                              ushort* __restrict__ Wqkb,
                                              ushort* __restrict__ Gcat,
                                              ushort* __restrict__ Fcs,
                                              ushort* __restrict__ Bas) {
    __shared__ float tc[128], ts[128];
    int tid = threadIdx.x;
    int bid = blockIdx.x;
    if (bid < 4096) {
        int i = bid * 256 + tid;
        float4 v = ((const float4*)x)[i];
        __hip_bfloat16 o[4] = {__float2bfloat16(v.x), __float2bfloat16(v.y),
                               __float2bfloat16(v.z), __float2bfloat16(v.w)};
        *(ushort4*)((ushort*)Xb + (size_t)i * 4) = *(const ushort4*)o;
    } else if (bid < 4224) {
        int u = bid - 4096;                // 0..127
        float4 v = *(const float4*)(wqkv + (size_t)u * 3072 + 2048 + tid * 4);
        ushort o[4] = {f2bfu(v.x), f2bfu(v.y), f2bfu(v.z), f2bfu(v.w)};
        *(ushort4*)(Wvb + (size_t)u * 1024 + tid * 4) = *(const ushort4*)o;
    } else if (bid < 4352) {
        int u = bid - 4224;                // 0..127: q/k cols 0..2047 of row u
        #pragma unroll
        for (int it = 0; it < 2; ++it) {
            int i = it * 256 + tid;        // float4 idx 0..511
            float4 v = ((const float4*)(wqkv + (size_t)u * 3072))[i];
            ushort o[4] = {f2bfu(v.x), f2bfu(v.y), f2bfu(v.z), f2bfu(v.w)};
            *(ushort4*)(Wqkb + (size_t)u * 2048 + i * 4) = *(const ushort4*)o;
        }
    } else if (bid < 4872) {
        int hx = bid - 4352;               // 0..519
        if (tid < 128) {
            float a = (float)tid / 64.0f;
            tc[tid] = cospif(a);
            ts[tid] = sinpif(a);
        }
        __syncthreads();
        if (tid < 128) {
            int h = hx / 65, xx = hx - h * 65;
            float w = (xx == 0 || xx == 64) ? (1.0f / 128.0f) : (2.0f / 128.0f);
            float ar = 0.f, ai = 0.f;
            #pragma unroll 8
            for (int d = 0; d < 128; ++d) {
                float wv = wout[(size_t)(h * 128 + d) * 128 + tid];
                int m = (xx * d) & 127;
                ar = fmaf(wv, tc[m], ar);
                ai = fmaf(wv, ts[m], ai);
            }
            ushort* gp = Gcat + ((size_t)(h * 128 + tid)) * 160;
            gp[xx] = f2bfu(ar * w);
            gp[80 + xx] = f2bfu(-ai * w);
            if (xx == 0) {
                for (int k = 65; k < 80; ++k) gp[k] = 0;
                for (int k = 145; k < 160; ++k) gp[k] = 0;
            }
        }
    } else if (bid < 4888) {
        // Fcs[r][y]: r<128 cos(2pi r y/128); r>=128 -sin(...); y>=65 -> 0
        int r = (bid - 4872) * 16 + (tid >> 4);
        int d = r & 127;
        int y0 = (tid & 15) * 6;
        #pragma unroll
        for (int k = 0; k < 6; ++k) {
            int y = y0 + k;
            float v = 0.f;
            if (y < 65) {
                float a = (float)((d * y) & 127) / 64.0f;
                v = (r < 128) ? cospif(a) : -sinpif(a);
            }
            Fcs[r * 96 + y] = f2bfu(v);
        }
    } else {
        // Bas[rj][d]: rj<80 -> cos(2pi f d/128)/65, rj>=80 -> -sin(...)/65, f=rj%80
        int idx = bid - 4888;              // 0..9
        int rj = idx * 16 + (tid >> 4);
        int ri = (rj >= 80) ? 1 : 0;
        int f = rj - ri * 80;
        int d0 = (tid & 15) * 8;
        #pragma unroll
        for (int k = 0; k < 8; ++k) {
            int d = d0 + k;
            float a = (float)((f * d) & 127) / 64.0f;
            float v = (ri ? -sinpif(a) : cospif(a)) * (1.0f / 65.0f);
            Bas[rj * 128 + d] = f2bfu(v);
        }
    }
}

// ---------------------------------------------------------------------------
// Weight DFT fold via MFMA. Grid 32: one block per (reg,h,uh): 64 u-rows.
// C[u][rj] = sum_d Wqkb[u][reg*1024+h*128+d] * Bas[rj][d]. M=64, N=160, K=128.
// Per-head layout Wt2[h][n = reg*160 + rj][u], rj = f + 80*ri.
// ---------------------------------------------------------------------------
__global__ __launch_bounds__(256) void k_wfold(const ushort* __restrict__ Wqkb,
                                               const ushort* __restrict__ Bas,
                                               ushort* __restrict__ Wt2) {
    __shared__ ushort As[64 * 128];
    __shared__ ushort Bs[160 * 128];
    int tid = threadIdx.x;
    int wave = tid >> 6, lane = tid & 63;
    int reg = blockIdx.x >> 4;
    int h = (blockIdx.x >> 1) & 7;
    int uh = blockIdx.x & 1;
    const ushort* ga = Wqkb + (size_t)(uh * 64) * 2048 + reg * 1024 + h * 128;
    #pragma unroll
    for (int it = 0; it < 4; ++it) {
        int q0 = wave * 256 + it * 64;
        int q = q0 + lane;
        int row = q >> 4, cp = q & 15;
        int gc = cp ^ (row & 15);
        g2l16(ga + (size_t)row * 2048 + gc * 8, As + q0 * 8);
    }
    #pragma unroll
    for (int it = 0; it < 10; ++it) {
        int q0 = it * 256 + wave * 64;
        int q = q0 + lane;
        int row = q >> 4, cp = q & 15;
        int gc = cp ^ (row & 15);
        g2l16(Bas + (size_t)row * 128 + gc * 8, Bs + q0 * 8);
    }
    __syncthreads();

    f32x4 acc[2][5];
    #pragma unroll
    for (int i = 0; i < 2; ++i)
        #pragma unroll
        for (int j = 0; j < 5; ++j) acc[i][j] = (f32x4){0.f, 0.f, 0.f, 0.f};

    int lr = lane & 15, lk = lane >> 4;
    int wr = (wave >> 1) * 32;             // m (u) offset within 64
    int wn = (wave & 1) * 80;              // n (rj) offset
    #pragma unroll
    for (int kk = 0; kk < 4; ++kk) {
        bf16x8 af[2], bfr[5];
        int c = kk * 4 + lk;
        #pragma unroll
        for (int i = 0; i < 2; ++i) {
            int m = wr + i * 16 + lr;
            af[i] = *(const bf16x8*)(As + m * 128 + (c ^ (m & 15)) * 8);
        }
        #pragma unroll
        for (int j = 0; j < 5; ++j) {
            int n = wn + j * 16 + lr;
            bfr[j] = *(const bf16x8*)(Bs + n * 128 + (c ^ (n & 15)) * 8);
        }
        #pragma unroll
        for (int i = 0; i < 2; ++i)
            #pragma unroll
            for (int j = 0; j < 5; ++j)
                acc[i][j] = __builtin_amdgcn_mfma_f32_16x16x32_bf16(af[i], bfr[j], acc[i][j], 0, 0, 0);
    }

    #pragma unroll
    for (int j = 0; j < 5; ++j) {
        int rj = wn + j * 16 + lr;
        int n = (h * 2 + reg) * 160 + rj;
        #pragma unroll
        for (int i = 0; i < 2; ++i) {
            int c0 = uh * 64 + wr + i * 16 + lk * 4;
            union { ushort4 u4; ushort u[4]; } pk;
            #pragma unroll
            for (int r = 0; r < 4; ++r) pk.u[r] = f2bfu(acc[i][j][r]);
            *(ushort4*)(Wt2 + (size_t)n * 128 + c0) = pk.u4;
        }
    }
}

// ---------------------------------------------------------------------------
// FUSED gemm1 + magnitude + QK^T, v7 — the measured-best variant (round 14,
// total 141.2 us). 640 thr / 10 waves, 72 KB LDS, 2 blocks/CU = 20 waves/CU.
// Wave (g,half): stage1 computes the q-pair or k-pair of freq-tile g
// (bw[4][2] loaded once); QK^T covers kt subset {0,1,2}/{3,4} with disjoint
// accumulators (numerically identical to v3). v9's launch_bounds(,8) spill
// trap and v8's setprio (null) both reverted.
// ---------------------------------------------------------------------------
__global__ __launch_bounds__(640, 2) void k_fuse(const __hip_bfloat16* __restrict__ Xb,
                                                 const ushort* __restrict__ Wt2,
                                                 float* __restrict__ attp) {
    __shared__ ushort As[128 * 128];    // 32 KB
    __shared__ ushort S[160 * 128];     // 40 KB
    int tid = threadIdx.x;
    int wave = tid >> 6, lane = tid & 63;   // 10 waves
    int lr = lane & 15, lk = lane >> 4;
    int g = wave >> 1;                      // freq-tile 0..4
    int half = wave & 1;                    // stage1 rb-half / QK^T kt-half
    int lin = blockIdx.y * 128 + blockIdx.x;
    int nl = (lin & 7) * 64 + (lin >> 3);   // bijective: 512 = 8*64
    int b = nl >> 5;                        // XCD gets 2 b's: X slices L2-local
    int epart = (nl >> 3) & 3, h = nl & 7;
    size_t erow0 = (size_t)b * NSEQ + (size_t)epart * 512;
    const ushort* wh = Wt2 + (size_t)h * 320 * 128;

    // B-fragments: wave (g,half) holds rb = half*2 + j (j=0 re, j=1 im)
    bf16x8 bw[4][2];
    #pragma unroll
    for (int ks = 0; ks < 4; ++ks)
        #pragma unroll
        for (int j = 0; j < 2; ++j) {
            int n = (half * 2 + j) * 80 + g * 16 + lr;
            bw[ks][j] = *(const bf16x8*)(wh + (size_t)n * 128 + (ks * 4 + lk) * 8);
        }

    // stage As(0): 128 e-rows, 2048 16B-chunks over 10 waves
    {
        const ushort* gx = (const ushort*)Xb + erow0 * 128;
        for (int r = wave; r < 32; r += 10) {
            int q0 = r * 64, q = q0 + lane;
            int row = q >> 4, cp = q & 15;
            int gc = cp ^ (row & 15);
            g2l16(gx + (size_t)row * 128 + gc * 8, As + q0 * 8);
        }
    }
    __syncthreads();

    f32x4 acc2[3];
    #pragma unroll
    for (int j = 0; j < 3; ++j) acc2[j] = (f32x4){0.f, 0.f, 0.f, 0.f};

    int srow = half * 80 + g * 16 + lr;    // stage-1 mag destination row
    int sw = (srow & 15);
    int ktb = half * 3;                    // QK^T kt base (0 or 3)
    int nkt = half ? 2 : 3;

    for (int it = 0; it < 4; ++it) {
        // ---- stage1 + mags: wave's (g, q/k) pair for all 128 e
        #pragma unroll
        for (int et = 0; et < 8; ++et) {
            f32x4 a2[2];
            a2[0] = (f32x4){0.f, 0.f, 0.f, 0.f};
            a2[1] = (f32x4){0.f, 0.f, 0.f, 0.f};
            #pragma unroll
            for (int ks = 0; ks < 4; ++ks) {
                int m = et * 16 + lr;
                bf16x8 xa = *(const bf16x8*)(As + m * 128 + (((ks * 4 + lk) ^ (m & 15))) * 8);
                a2[0] = __builtin_amdgcn_mfma_f32_16x16x32_bf16(xa, bw[ks][0], a2[0], 0, 0, 0);
                a2[1] = __builtin_amdgcn_mfma_f32_16x16x32_bf16(xa, bw[ks][1], a2[1], 0, 0, 0);
            }
            int e4 = et * 16 + lk * 4;
            int cq = e4 >> 3, sub = e4 & 7;
            union { ushort4 u4; ushort u[4]; } pm;
            #pragma unroll
            for (int r = 0; r < 4; ++r)
                pm.u[r] = f2bfu(__builtin_amdgcn_sqrtf(a2[0][r] * a2[0][r] + a2[1][r] * a2[1][r]));
            *(ushort4*)(S + srow * 128 + ((cq ^ sw) << 3) + sub) = pm.u4;
        }
        __syncthreads();                 // S complete; As reads done
        if (it < 3) {
            // prefetch As(it+1); latency hides under QK^T, drained at barrier
            const ushort* gx = (const ushort*)Xb + (erow0 + (size_t)(it + 1) * 128) * 128;
            for (int r = wave; r < 32; r += 10) {
                int q0 = r * 64, q = q0 + lane;
                int row = q >> 4, cp = q & 15;
                int gc = cp ^ (row & 15);
                g2l16(gx + (size_t)row * 128 + gc * 8, As + q0 * 8);
            }
        }
        // ---- QK^T: wave (g,half) -> q-tile g, kt subset, K=128 (this iter)
        #pragma unroll
        for (int ks = 0; ks < 4; ++ks) {
            int cg = ks * 4 + lk;
            int xr = g * 16 + lr;
            bf16x8 qa = *(const bf16x8*)(S + xr * 128 + ((cg ^ (xr & 15)) << 3));
            #pragma unroll
            for (int j = 0; j < 3; ++j) {
                if (j < nkt) {
                    int kt = ktb + j;
                    int yr = 80 + kt * 16 + lr;
                    bf16x8 kb = *(const bf16x8*)(S + yr * 128 + ((cg ^ (yr & 15)) << 3));
                    acc2[j] = __builtin_amdgcn_mfma_f32_16x16x32_bf16(qa, kb, acc2[j], 0, 0, 0);
                }
            }
        }
        __syncthreads();                 // S reads done; As(it+1) drained
    }

    float* outp = attp + ((size_t)(b * 8 + h) * 4 + epart) * 6400;
    #pragma unroll
    for (int j = 0; j < 3; ++j) {
        if (j < nkt) {
            int kt = ktb + j;
            #pragma unroll
            for (int r = 0; r < 4; ++r)
                outp[(g * 16 + lk * 4 + r) * 80 + kt * 16 + lr] = acc2[j][r];
        }
    }
}

// ---------------------------------------------------------------------------
// Sum 4 partials + softmax over y -> AttB bf16 [80x104] zero-padded.
// ---------------------------------------------------------------------------
__global__ void k_softmax(const float* __restrict__ attp, ushort* __restrict__ AttB) {
    int xx = blockIdx.x;                   // 0..79
    int bh = blockIdx.y;                   // 0..127
    int lane = threadIdx.x;                // 64
    ushort* Ab = AttB + (size_t)bh * 8320;
    if (xx >= 65) {
        Ab[xx * 104 + lane] = 0;
        if (lane < 40) Ab[xx * 104 + 64 + lane] = 0;
        return;
    }
    const float* base = attp + (size_t)bh * 4 * 6400 + xx * 80;
    float v0 = 0.f, v1 = 0.f;
    #pragma unroll
    for (int c = 0; c < 4; ++c) {
        v0 += base[(size_t)c * 6400 + lane];
        if (lane == 0) v1 += base[(size_t)c * 6400 + 64];
    }
    float v1b = __shfl(v1, 0);
    float m = fmaxf(v0, v1b);
    #pragma unroll
    for (int off = 32; off >= 1; off >>= 1) m = fmaxf(m, __shfl_xor(m, off));
    float e0 = expf(v0 - m);
    float e1 = expf(v1b - m);
    float s = e0;
    #pragma unroll
    for (int off = 32; off >= 1; off >>= 1) s += __shfl_xor(s, off);
    s += e1;
    float inv = 1.0f / s;
    Ab[xx * 104 + lane] = f2bfu(e0 * inv);
    if (lane == 0) Ab[xx * 104 + 64] = f2bfu(e1 * inv);
    if (lane < 39) Ab[xx * 104 + 65 + lane] = 0;
}

// ---------------------------------------------------------------------------
// Fused T+P per (chalf, bh) block (reads bf16 AttB straight from global):
// Stage 1: [Fc;Fs][256,96] @ AttB^T -> A3 via LDS (C->A layout, pads zeroed)
// Stage 2: A3[128,160] @ Gcat^T -> Pt[b][c][h*128+d]
// ---------------------------------------------------------------------------
__global__ __launch_bounds__(256) void k_TP(const ushort* __restrict__ AttB,
                                            const ushort* __restrict__ Fcs,
                                            const ushort* __restrict__ Gcat,
                                            ushort* __restrict__ Pt) {
    __shared__ ushort A3[128 * 168];
    int tid = threadIdx.x;
    int wave = tid >> 6, lane = tid & 63;
    int lr = lane & 15, quad = lane >> 4;
    int chalf = blockIdx.x, bh = blockIdx.y;
    int b = bh >> 3, h = bh & 7;

    uint2 z2; z2.x = 0; z2.y = 0;
    uint2* A3v = (uint2*)A3;
    #pragma unroll 4
    for (int i = tid; i < 128 * 168 / 4; i += 256) A3v[i] = z2;
    __syncthreads();
    const ushort* Ab = AttB + (size_t)bh * 8320;

    // stage 1
    f32x4 acc1[4][5];
    #pragma unroll
    for (int i = 0; i < 4; ++i)
        #pragma unroll
        for (int j = 0; j < 5; ++j) acc1[i][j] = (f32x4){0.f, 0.f, 0.f, 0.f};
    #pragma unroll
    for (int ks = 0; ks < 3; ++ks) {
        bf16x8 af[4], bfr[5];
        #pragma unroll
        for (int mi = 0; mi < 4; ++mi)
            af[mi] = *(const bf16x8*)(Fcs + (size_t)((wave * 4 + mi) * 16 + lr) * 96 + ks * 32 + quad * 8);
        #pragma unroll
        for (int nt = 0; nt < 5; ++nt)
            bfr[nt] = *(const bf16x8*)(Ab + (nt * 16 + lr) * 104 + ks * 32 + quad * 8);
        #pragma unroll
        for (int mi = 0; mi < 4; ++mi)
            #pragma unroll
            for (int nt = 0; nt < 5; ++nt)
                acc1[mi][nt] = __builtin_amdgcn_mfma_f32_16x16x32_bf16(af[mi], bfr[nt], acc1[mi][nt], 0, 0, 0);
    }
    #pragma unroll
    for (int nt = 0; nt < 5; ++nt) {
        int x = nt * 16 + lr;
        if (x < 65) {
            #pragma unroll
            for (int mi = 0; mi < 4; ++mi) {
                int wbase = (wave * 4 + mi) * 16 + quad * 4;
                #pragma unroll
                for (int r = 0; r < 4; ++r) {
                    int which = wbase + r;
                    int d = which & 127;
                    int kc = (which >> 7) * 80 + x;
                    A3[d * 168 + kc] = f2bfu(acc1[mi][nt][r]);
                }
            }
        }
    }
    __syncthreads();

    // stage 2
    f32x4 acc2[2][4];
    #pragma unroll
    for (int i = 0; i < 2; ++i)
        #pragma unroll
        for (int j = 0; j < 4; ++j) acc2[i][j] = (f32x4){0.f, 0.f, 0.f, 0.f};
    const ushort* Gh = Gcat + (size_t)h * 128 * 160;
    #pragma unroll
    for (int ks = 0; ks < 5; ++ks) {
        bf16x8 a2[2], b2[4];
        #pragma unroll
        for (int mi = 0; mi < 2; ++mi)
            a2[mi] = *(const bf16x8*)(A3 + ((wave * 2 + mi) * 16 + lr) * 168 + ks * 32 + quad * 8);
        #pragma unroll
        for (int nt = 0; nt < 4; ++nt)
            b2[nt] = *(const bf16x8*)(Gh + (size_t)(chalf * 64 + nt * 16 + lr) * 160 + ks * 32 + quad * 8);
        #pragma unroll
        for (int mi = 0; mi < 2; ++mi)
            #pragma unroll
            for (int nt = 0; nt < 4; ++nt)
                acc2[mi][nt] = __builtin_amdgcn_mfma_f32_16x16x32_bf16(a2[mi], b2[nt], acc2[mi][nt], 0, 0, 0);
    }
    #pragma unroll
    for (int mi = 0; mi < 2; ++mi) {
        int dbase = (wave * 2 + mi) * 16 + quad * 4;
        #pragma unroll
        for (int nt = 0; nt < 4; ++nt) {
            int c = chalf * 64 + nt * 16 + lr;
            union { ushort4 u4; ushort u[4]; } pk;
            #pragma unroll
            for (int r = 0; r < 4; ++r) pk.u[r] = f2bfu(acc2[mi][nt][r]);
            *(ushort4*)(Pt + ((size_t)(b * 128 + c)) * 1024 + h * 128 + dbase) = pk.u4;
        }
    }
}

// ---------------------------------------------------------------------------
// R_b = Wv @ P_b folded: Rt_b[n][u] = sum_vc Wvb[u][vc] * Pt_b[n][vc].
// Grid 64: (b, nq, uq) -> 64x64 output quadrant.
// ---------------------------------------------------------------------------
__global__ __launch_bounds__(256) void k_R(const ushort* __restrict__ Wvb,
                                           const ushort* __restrict__ Pt,
                                           ushort* __restrict__ Rt) {
    __shared__ ushort As[64 * 128];
    __shared__ ushort Bs[64 * 128];
    int tid = threadIdx.x;
    int wave = tid >> 6, lane = tid & 63;
    int b = blockIdx.x >> 2;
    int nq = (blockIdx.x >> 1) & 1;
    int uq = blockIdx.x & 1;
    const ushort* pb = Pt + (size_t)b * 128 * 1024;

    f32x4 acc[2][2];
    #pragma unroll
    for (int i = 0; i < 2; ++i)
        #pragma unroll
        for (int j = 0; j < 2; ++j) acc[i][j] = (f32x4){0.f, 0.f, 0.f, 0.f};

    int lr = lane & 15, lk = lane >> 4;
    int wr = (wave >> 1) * 32, wc = (wave & 1) * 32;

    for (int k0 = 0; k0 < 1024; k0 += 128) {
        __syncthreads();
        #pragma unroll
        for (int it = 0; it < 4; ++it) {
            int q = wave * 256 + it * 64 + lane;
            int row = q >> 4, cp = q & 15;
            int gc = cp ^ (row & 15);
            int lbase = (wave * 256 + it * 64) * 8;
            g2l16(Wvb + (size_t)(uq * 64 + row) * 1024 + k0 + gc * 8, As + lbase);
            g2l16(pb + (size_t)(nq * 64 + row) * 1024 + k0 + gc * 8, Bs + lbase);
        }
        __syncthreads();
        #pragma unroll
        for (int kk = 0; kk < 4; ++kk) {
            bf16x8 af[2], bfr[2];
            int c = kk * 4 + lk;
            #pragma unroll
            for (int i = 0; i < 2; ++i) {
                int m = wr + i * 16 + lr;
                af[i] = *(const bf16x8*)(As + m * 128 + (c ^ (m & 15)) * 8);
                int n = wc + i * 16 + lr;
                bfr[i] = *(const bf16x8*)(Bs + n * 128 + (c ^ (n & 15)) * 8);
            }
            #pragma unroll
            for (int i = 0; i < 2; ++i)
                #pragma unroll
                for (int j = 0; j < 2; ++j)
                    acc[i][j] = __builtin_amdgcn_mfma_f32_16x16x32_bf16(af[i], bfr[j], acc[i][j], 0, 0, 0);
        }
    }
    #pragma unroll
    for (int i = 0; i < 2; ++i) {
        int ubase = uq * 64 + wr + i * 16 + lk * 4;
        #pragma unroll
        for (int j = 0; j < 2; ++j) {
            int n = nq * 64 + wc + j * 16 + lr;
            union { ushort4 u4; ushort u[4]; } pk;
            #pragma unroll
            for (int r = 0; r < 4; ++r) pk.u[r] = f2bfu(acc[i][j][r]);
            *(ushort4*)(Rt + (size_t)b * 16384 + n * 128 + ubase) = pk.u4;
        }
    }
}

// ---------------------------------------------------------------------------
// out = Xb @ Rt_b^T + bias. M=32768 (128/block), N=128, K=128 one shot.
// ---------------------------------------------------------------------------
__global__ __launch_bounds__(256) void k_out(const __hip_bfloat16* __restrict__ Xb,
                                             const ushort* __restrict__ Rt,
                                             const float* __restrict__ bout,
                                             float* __restrict__ out) {
    __shared__ ushort As[128 * 128];
    __shared__ ushort Bs[128 * 128];
    int tid = threadIdx.x;
    int wave = tid >> 6, lane = tid & 63;
    int m0 = blockIdx.x * 128;
    int b = blockIdx.x >> 4;
    const ushort* ga = (const ushort*)Xb + (size_t)m0 * 128;
    const ushort* gb = Rt + (size_t)b * 16384;
    #pragma unroll
    for (int it = 0; it < 8; ++it) {
        int q = wave * 512 + it * 64 + lane;
        int row = q >> 4, cp = q & 15;
        int gc = cp ^ (row & 15);
        int lbase = (wave * 512 + it * 64) * 8;
        g2l16(ga + (size_t)row * 128 + gc * 8, As + lbase);
        g2l16(gb + (size_t)row * 128 + gc * 8, Bs + lbase);
    }
    __syncthreads();

    f32x4 acc[4][4];
    #pragma unroll
    for (int i = 0; i < 4; ++i)
        #pragma unroll
        for (int j = 0; j < 4; ++j) acc[i][j] = (f32x4){0.f, 0.f, 0.f, 0.f};

    int lr = lane & 15, lk = lane >> 4;
    int wr = (wave >> 1) * 64, wc = (wave & 1) * 64;
    #pragma unroll
    for (int kk = 0; kk < 4; ++kk) {
        bf16x8 af[4], bfr[4];
        int c = kk * 4 + lk;
        #pragma unroll
        for (int i = 0; i < 4; ++i) {
            int m = wr + i * 16 + lr;
            af[i] = *(const bf16x8*)(As + m * 128 + (c ^ (m & 15)) * 8);
            int n = wc + i * 16 + lr;
            bfr[i] = *(const bf16x8*)(Bs + n * 128 + (c ^ (n & 15)) * 8);
        }
        #pragma unroll
        for (int i = 0; i < 4; ++i)
            #pragma unroll
            for (int j = 0; j < 4; ++j)
                acc[i][j] = __builtin_amdgcn_mfma_f32_16x16x32_bf16(af[i], bfr[j], acc[i][j], 0, 0, 0);
    }

    #pragma unroll
    for (int i = 0; i < 4; ++i) {
        int gr = m0 + wr + i * 16 + lk * 4;
        #pragma unroll
        for (int j = 0; j < 4; ++j) {
            int gcol = wc + j * 16 + lr;
            float bias = bout[gcol];
            #pragma unroll
            for (int r = 0; r < 4; ++r)
                out[(size_t)(gr + r) * 128 + gcol] = acc[i][j][r] + bias;
        }
    }
}

extern "C" void kernel_launch(void* const* d_in, const int* in_sizes, int n_in,
                              void* d_out, int out_size, void* d_ws, size_t ws_size,
                              hipStream_t stream) {
    const float* x    = (const float*)d_in[0];
    const float* wqkv = (const float*)d_in[1];
    const float* wout = (const float*)d_in[2];
    const float* bout = (const float*)d_in[3];
    float* out = (float*)d_out;

    char* ws = (char*)d_ws;
    size_t off = 0;
    auto alloc = [&](size_t bytes) -> void* {
        void* p = (void*)(ws + off);
        off += (bytes + 255) & ~(size_t)255;
        return p;
    };
    ushort* Wt2  = (ushort*)alloc((size_t)8 * 320 * 128 * 2);                  // 640 KB
    ushort* Gcat = (ushort*)alloc((size_t)8 * 128 * 160 * 2);                  // 320 KB
    ushort* Fcs  = (ushort*)alloc((size_t)256 * 96 * 2);                       // 48 KB
    ushort* Wvb  = (ushort*)alloc((size_t)128 * 1024 * 2);                     // 256 KB
    ushort* Wqkb = (ushort*)alloc((size_t)128 * 2048 * 2);                     // 512 KB
    ushort* Bas  = (ushort*)alloc((size_t)160 * 128 * 2);                      // 40 KB
    __hip_bfloat16* Xb = (__hip_bfloat16*)alloc((size_t)MROWS * 128 * 2);      // 8.4 MB
    float* attp = (float*)alloc((size_t)128 * 4 * 6400 * 4);                   // 13.1 MB
    ushort* AttB = (ushort*)alloc((size_t)128 * 8320 * 2);                     // 2.13 MB
    ushort* Pt  = (ushort*)alloc((size_t)16 * 128 * 1024 * 2);                 // 4.2 MB
    ushort* Rt  = (ushort*)alloc((size_t)16 * 128 * 128 * 2);                  // 512 KB

    k_misc<<<dim3(4898), 256, 0, stream>>>(x, wqkv, wout, Xb, Wvb, Wqkb, Gcat, Fcs, Bas);
    k_wfold<<<dim3(32), 256, 0, stream>>>(Wqkb, Bas, Wt2);
    k_fuse<<<dim3(128, 4), 640, 0, stream>>>(Xb, Wt2, attp);
    k_softmax<<<dim3(80, 128), 64, 0, stream>>>(attp, AttB);
    k_TP<<<dim3(2, 128), 256, 0, stream>>>(AttB, Fcs, Gcat, Pt);
    k_R<<<dim3(64), 256, 0, stream>>>(Wvb, Pt, Rt);
    k_out<<<dim3(256), 256, 0, stream>>>(Xb, Rt, bout, out);
}